// Round 7
// baseline (1345.097 us; speedup 1.0000x reference)
//
#include <hip/hip_runtime.h>
#include <hip/hip_bf16.h>
#include <math.h>

#define T_ 12
#define E_ 8192
#define H_ 256
#define V_ 800
#define B_ 256
#define NB_ 8
#define M_ (T_*E_)
#define TM 16            // message rows per block per step
#define HP (H_ + 8)      // bf16 LDS row pad
#define NBLK 512         // persistent grid: 2 blocks/CU on 256 CUs (proven resident R4-R6)

typedef __attribute__((ext_vector_type(8))) short bf16x8;
typedef __attribute__((ext_vector_type(4))) float f32x4;
typedef unsigned long long u64;

#define LOG2E_ 1.44269504088896f

// fast native transcendentals (v_exp_f32 = 2^x, v_rcp_f32)
__device__ __forceinline__ float fexp2_(float x) { return __builtin_amdgcn_exp2f(x); }
__device__ __forceinline__ float frcp_(float x)  { return __builtin_amdgcn_rcpf(x); }
__device__ __forceinline__ float fsig(float x) {
    return frcp_(1.0f + fexp2_(-LOG2E_ * x));
}
__device__ __forceinline__ float ftanh(float x) {
    // tanh(x) = 1 - 2/(exp(2x)+1); large |x| saturates correctly via inf/0
    return 1.0f - 2.0f * frcp_(fexp2_(2.0f * LOG2E_ * x) + 1.0f);
}

// RNE f32 -> bf16 bits
__device__ __forceinline__ short f2bf(float x) {
    unsigned u = __float_as_uint(x);
    unsigned r = (u + 0x7fffu + ((u >> 16) & 1u)) >> 16;
    return (short)r;
}
__device__ __forceinline__ float bf2f(unsigned short s) {
    return __uint_as_float(((unsigned)s) << 16);
}
// packed word: lo16 -> float via <<16, hi16 -> float via mask
__device__ __forceinline__ float hu_h(unsigned v) { return __uint_as_float(v << 16); }
__device__ __forceinline__ float hu_u(unsigned v) { return __uint_as_float(v & 0xffff0000u); }
__device__ __forceinline__ unsigned pack2(float a, float b) {
    return (unsigned)(unsigned short)f2bf(a) | ((unsigned)(unsigned short)f2bf(b) << 16);
}

// Agent-scope (device-coherent) STORES for cross-block data (hu, h): they land at
// the coherence point so later first-touch cached reads (other XCDs) see them.
// GATHER LOADS are normal cached loads: each hu row is written exactly once, >=1
// grid barrier before any read (nei_idx at depth t only references depths < t),
// so no L1/L2 can hold a stale copy on first touch.
__device__ __forceinline__ void co_store64(u64* p, u64 v) {
    __hip_atomic_store(p, v, __ATOMIC_RELAXED, __HIP_MEMORY_SCOPE_AGENT);
}
__device__ __forceinline__ float co_loadf(const float* p) {
    return __uint_as_float(__hip_atomic_load((const unsigned*)p, __ATOMIC_RELAXED, __HIP_MEMORY_SCOPE_AGENT));
}

// Fence-free grid barrier for a fully-resident grid (R6-proven). __syncthreads
// drains vmcnt (agent stores complete at the coherence point before any wave
// passes); counter==target implies all cross-step data is globally visible.
__device__ __forceinline__ void gbar(unsigned* cnt, unsigned target) {
    __syncthreads();
    if (threadIdx.x == 0) {
        __hip_atomic_fetch_add(cnt, 1u, __ATOMIC_RELAXED, __HIP_MEMORY_SCOPE_AGENT);
        while (__hip_atomic_load(cnt, __ATOMIC_RELAXED, __HIP_MEMORY_SCOPE_AGENT) < target)
            __builtin_amdgcn_s_sleep(8);
    }
    __syncthreads();
}

// Weight prep (+ slot-0 init and barrier-counter reset folded into block 768).
// Wzt[n][k] = Wz[256+k][n], Wht[n][k] = Wh[256+k][n], Urt[n][k] = Ur[k][n], bf16.
__global__ __launch_bounds__(256) void k_wconv(
    const float* __restrict__ Wz, const float* __restrict__ Wh, const float* __restrict__ Ur,
    short* __restrict__ Wzt, short* __restrict__ Wht, short* __restrict__ Urt,
    float* __restrict__ h, unsigned* __restrict__ hu, unsigned* __restrict__ bar)
{
    if (blockIdx.x == 768) {            // zero padding row (slot 0) of h and hu
        h[threadIdx.x] = 0.0f;
        hu[threadIdx.x] = 0u;
        if (threadIdx.x == 0) bar[0] = 0u;   // re-zero barrier each graph replay
        return;
    }
    int tid = blockIdx.x * 256 + threadIdx.x;
    int w = tid >> 16;
    int idx = tid & 65535;
    int n = idx >> 8, k = idx & 255;
    if (w == 0)      Wzt[idx] = f2bf(Wz[(size_t)(256 + k) * H_ + n]);
    else if (w == 1) Wht[idx] = f2bf(Wh[(size_t)(256 + k) * H_ + n]);
    else             Urt[idx] = f2bf(Ur[(size_t)k * H_ + n]);
}

// Batched prelude: eW*[v] = emb[v] @ Btop + bias  (blockIdx.z selects table)
__global__ __launch_bounds__(256) void gemm_pre(
    const float* __restrict__ emb,
    const float* __restrict__ Wr, const float* __restrict__ Wz,
    const float* __restrict__ Wh, const float* __restrict__ Wo,
    const float* __restrict__ bur, const float* __restrict__ bz,
    const float* __restrict__ bh, const float* __restrict__ bo,
    float* __restrict__ eWr, float* __restrict__ eWz,
    float* __restrict__ eWh, float* __restrict__ eWo)
{
    const float* Bm; const float* bias; float* C;
    switch (blockIdx.z) {
        case 0: Bm = Wr; bias = bur; C = eWr; break;
        case 1: Bm = Wz; bias = bz;  C = eWz; break;
        case 2: Bm = Wh; bias = bh;  C = eWh; break;
        default: Bm = Wo; bias = bo; C = eWo; break;
    }
    __shared__ float As[16][64];
    __shared__ float Bs[16][64];
    const int tid = threadIdx.x;
    const int bm = blockIdx.x * 64;
    const int bn = blockIdx.y * 64;
    const int a_m = tid & 63;
    const int a_k = (tid >> 6) << 2;
    const int b_k = tid >> 4;
    const int b_n = (tid & 15) << 2;
    const int tx = tid & 15, ty = tid >> 4;

    float acc[4][4] = {};
    const bool a_ok = (bm + a_m) < V_;
    const float* Ap = emb + (size_t)(bm + a_m) * H_ + a_k;
    const float* Bp = Bm + (size_t)b_k * H_ + bn + b_n;

    for (int k0 = 0; k0 < H_; k0 += 16) {
        float4 av = a_ok ? *(const float4*)(Ap + k0) : make_float4(0.f, 0.f, 0.f, 0.f);
        float4 bv = *(const float4*)(Bp + (size_t)k0 * H_);
        __syncthreads();
        As[a_k + 0][a_m] = av.x;
        As[a_k + 1][a_m] = av.y;
        As[a_k + 2][a_m] = av.z;
        As[a_k + 3][a_m] = av.w;
        *(float4*)&Bs[b_k][b_n] = bv;
        __syncthreads();
#pragma unroll
        for (int k = 0; k < 16; ++k) {
            const float4 a4 = *(const float4*)&As[k][ty << 2];
            const float4 b4 = *(const float4*)&Bs[k][tx << 2];
            const float ar[4] = {a4.x, a4.y, a4.z, a4.w};
            const float br[4] = {b4.x, b4.y, b4.z, b4.w};
#pragma unroll
            for (int i = 0; i < 4; ++i)
#pragma unroll
                for (int j = 0; j < 4; ++j)
                    acc[i][j] = fmaf(ar[i], br[j], acc[i][j]);
        }
    }

    const int col = bn + (tx << 2);
#pragma unroll
    for (int i = 0; i < 4; ++i) {
        const int row = bm + (ty << 2) + i;
        if (row >= V_) break;
        *(float4*)(C + (size_t)row * H_ + col) =
            make_float4(acc[i][0] + bias[col], acc[i][1] + bias[col + 1],
                        acc[i][2] + bias[col + 2], acc[i][3] + bias[col + 3]);
    }
}

// Pack epilogue tables: eWzh = {lo16: bf16(eWz), hi16: bf16(eWh)}
__global__ __launch_bounds__(256) void k_pack(
    const float* __restrict__ eWz, const float* __restrict__ eWh,
    unsigned* __restrict__ eWzh)
{
    const int i = blockIdx.x * 256 + threadIdx.x;   // V_*H_ = 204800 = 800*256
    eWzh[i] = pack2(eWz[i], eWh[i]);
}

// Persistent kernel: all 12 steps + root aggregation. Cached gather loads,
// LDS-staged coalesced agent-scope h/hu writes, fence-free grid barrier.
__global__ __launch_bounds__(512, 4) void k_steps_all(
    const int* __restrict__ x_ids, const int* __restrict__ nei_idx,
    float* __restrict__ h, unsigned* __restrict__ hu,
    const float* __restrict__ eWr, const unsigned* __restrict__ eWzh,
    const short* __restrict__ Wzt, const short* __restrict__ Wht,
    const short* __restrict__ Urt,
    const int* __restrict__ root_wid, const int* __restrict__ root_nei,
    const float* __restrict__ eWo, const float* __restrict__ Wo,
    float* __restrict__ root_out, unsigned* __restrict__ bar)
{
    __shared__ int   idx[TM][NB_];
    __shared__ int   xw[TM];
    __shared__ short shB[TM][HP];   // sumh bf16 (A-frag + epilogue linear term)
    __shared__ short sgB[TM][HP];   // sumg bf16 (A-frag)
    __shared__ short hB[TM][HP];    // h_t bf16 (A-frag Ur + hu pack)
    __shared__ short uB[TM][HP];    // u bf16 (hu pack)
    __shared__ float hF[TM][H_];    // h_t f32 (coalesced write staging)

    const int tid = threadIdx.x;
    const int e0 = blockIdx.x * TM;
    const int lane = tid & 63;
    const int wave = tid >> 6;           // 0..7
    const int n0 = wave * 32;
    const int quad = lane >> 4, c = lane & 15;
    const int kq = quad * 8;
    // coalesced write-phase mapping: thread -> (row, 8-col chunk)
    const int wr = tid >> 5;             // 16 rows
    const int wc = (tid & 31) * 8;       // 32 chunks x 8 cols

    for (int t = 0; t < T_; ++t) {
        if (tid < TM * NB_) {
            int r = tid >> 3, j = tid & 7;
            idx[r][j] = nei_idx[((size_t)t * E_ + e0 + r) * NB_ + j];
        }
        if (tid < TM) xw[tid] = x_ids[t * E_ + e0 + tid];
        __syncthreads();

        // ---- gather: thread = (4-col group, row pair); CACHED uint4 loads ----
        {
            const int c0 = (tid & 63) * 4;       // 64 col-groups x 4 cols = 256 cols
            const int ra = (tid >> 6) * 2;       // 8 row-pairs = 16 rows
            const int rb = ra + 1;
            if (t == 0) {
                // all neighbor slots are the zero pad at t=0
                *(uint2*)&shB[ra][c0] = make_uint2(0u, 0u);
                *(uint2*)&sgB[ra][c0] = make_uint2(0u, 0u);
                *(uint2*)&shB[rb][c0] = make_uint2(0u, 0u);
                *(uint2*)&sgB[rb][c0] = make_uint2(0u, 0u);
            } else {
                uint4 va[NB_], vb[NB_];
#pragma unroll
                for (int j = 0; j < NB_; ++j)
                    va[j] = *(const uint4*)(hu + (size_t)idx[ra][j] * H_ + c0);
#pragma unroll
                for (int j = 0; j < NB_; ++j)
                    vb[j] = *(const uint4*)(hu + (size_t)idx[rb][j] * H_ + c0);
                const float4 r1a = *(const float4*)(eWr + (size_t)xw[ra] * H_ + c0);
                const float4 r1b = *(const float4*)(eWr + (size_t)xw[rb] * H_ + c0);

                float sa0 = 0.f, sa1 = 0.f, sa2 = 0.f, sa3 = 0.f;
                float ga0 = 0.f, ga1 = 0.f, ga2 = 0.f, ga3 = 0.f;
#pragma unroll
                for (int j = 0; j < NB_; ++j) {
                    const float h0 = hu_h(va[j].x); sa0 += h0;
                    ga0 = fmaf(fsig(r1a.x + hu_u(va[j].x)), h0, ga0);
                    const float h1 = hu_h(va[j].y); sa1 += h1;
                    ga1 = fmaf(fsig(r1a.y + hu_u(va[j].y)), h1, ga1);
                    const float h2 = hu_h(va[j].z); sa2 += h2;
                    ga2 = fmaf(fsig(r1a.z + hu_u(va[j].z)), h2, ga2);
                    const float h3 = hu_h(va[j].w); sa3 += h3;
                    ga3 = fmaf(fsig(r1a.w + hu_u(va[j].w)), h3, ga3);
                }
                *(uint2*)&shB[ra][c0] = make_uint2(pack2(sa0, sa1), pack2(sa2, sa3));
                *(uint2*)&sgB[ra][c0] = make_uint2(pack2(ga0, ga1), pack2(ga2, ga3));

                float sb0 = 0.f, sb1 = 0.f, sb2 = 0.f, sb3 = 0.f;
                float gb0 = 0.f, gb1 = 0.f, gb2 = 0.f, gb3 = 0.f;
#pragma unroll
                for (int j = 0; j < NB_; ++j) {
                    const float h0 = hu_h(vb[j].x); sb0 += h0;
                    gb0 = fmaf(fsig(r1b.x + hu_u(vb[j].x)), h0, gb0);
                    const float h1 = hu_h(vb[j].y); sb1 += h1;
                    gb1 = fmaf(fsig(r1b.y + hu_u(vb[j].y)), h1, gb1);
                    const float h2 = hu_h(vb[j].z); sb2 += h2;
                    gb2 = fmaf(fsig(r1b.z + hu_u(vb[j].z)), h2, gb2);
                    const float h3 = hu_h(vb[j].w); sb3 += h3;
                    gb3 = fmaf(fsig(r1b.w + hu_u(vb[j].w)), h3, gb3);
                }
                *(uint2*)&shB[rb][c0] = make_uint2(pack2(sb0, sb1), pack2(sb2, sb3));
                *(uint2*)&sgB[rb][c0] = make_uint2(pack2(gb0, gb1), pack2(gb2, gb3));
            }
        }
        __syncthreads();

        // ---- MFMA + in-register epilogue: wave owns 32-col strip, both Z and H ----
        f32x4 accZ[2], accH[2];
#pragma unroll
        for (int i = 0; i < 2; ++i) { accZ[i] = (f32x4)(0.0f); accH[i] = (f32x4)(0.0f); }

#pragma unroll
        for (int k0 = 0; k0 < H_; k0 += 32) {
            const bf16x8 a1 = *(const bf16x8*)&shB[c][k0 + kq];
            const bf16x8 a2 = *(const bf16x8*)&sgB[c][k0 + kq];
#pragma unroll
            for (int ni = 0; ni < 2; ++ni) {
                const size_t boff = (size_t)(n0 + ni * 16 + c) * H_ + k0 + kq;
                const bf16x8 b1 = *(const bf16x8*)(Wzt + boff);
                const bf16x8 b2 = *(const bf16x8*)(Wht + boff);
                accZ[ni] = __builtin_amdgcn_mfma_f32_16x16x32_bf16(a1, b1, accZ[ni], 0, 0, 0);
                accH[ni] = __builtin_amdgcn_mfma_f32_16x16x32_bf16(a2, b2, accH[ni], 0, 0, 0);
            }
        }

        // epilogue: h_t = (1-z)*sumh + z*pre -> stage f32 + bf16 in LDS
#pragma unroll
        for (int reg = 0; reg < 4; ++reg) {
            const int r = quad * 4 + reg;
            const int xr = xw[r];
#pragma unroll
            for (int ni = 0; ni < 2; ++ni) {
                const int col = n0 + ni * 16 + c;
                const unsigned zh = eWzh[(size_t)xr * H_ + col];
                const float z   = fsig(accZ[ni][reg] + hu_h(zh));
                const float pre = ftanh(accH[ni][reg] + hu_u(zh));
                const float hv = (1.0f - z) * bf2f((unsigned short)shB[r][col]) + z * pre;
                hF[r][col] = hv;
                hB[r][col] = f2bf(hv);
            }
        }
        __syncthreads();

        if (t < T_ - 1) {
            // ---- Ur MFMA: u = h_t @ Ur -> stage u bf16 ----
            f32x4 accU[2];
            accU[0] = (f32x4)(0.0f); accU[1] = (f32x4)(0.0f);
#pragma unroll
            for (int k0 = 0; k0 < H_; k0 += 32) {
                const bf16x8 a = *(const bf16x8*)&hB[c][k0 + kq];
#pragma unroll
                for (int ni = 0; ni < 2; ++ni) {
                    const bf16x8 b = *(const bf16x8*)(Urt + (size_t)(n0 + ni * 16 + c) * H_ + k0 + kq);
                    accU[ni] = __builtin_amdgcn_mfma_f32_16x16x32_bf16(a, b, accU[ni], 0, 0, 0);
                }
            }
#pragma unroll
            for (int reg = 0; reg < 4; ++reg) {
                const int r = quad * 4 + reg;
#pragma unroll
                for (int ni = 0; ni < 2; ++ni)
                    uB[r][n0 + ni * 16 + c] = f2bf(accU[ni][reg]);
            }
            __syncthreads();

            // ---- coalesced write phase: full-line agent-scope stores ----
            float* h_t = h + (size_t)(1 + t * E_ + e0) * H_;
            unsigned* hu_t = hu + (size_t)(1 + t * E_ + e0) * H_;
            u64* hd = (u64*)(h_t + (size_t)wr * H_ + wc);
            u64* ud = (u64*)(hu_t + (size_t)wr * H_ + wc);
#pragma unroll
            for (int q = 0; q < 4; ++q)
                co_store64(hd + q, *(const u64*)&hF[wr][wc + 2 * q]);
#pragma unroll
            for (int q = 0; q < 4; ++q) {
                const unsigned lo = ((unsigned)(unsigned short)uB[wr][wc + 2 * q] << 16)
                                  | (unsigned short)hB[wr][wc + 2 * q];
                const unsigned hi = ((unsigned)(unsigned short)uB[wr][wc + 2 * q + 1] << 16)
                                  | (unsigned short)hB[wr][wc + 2 * q + 1];
                co_store64(ud + q, (u64)lo | ((u64)hi << 32));
            }
        } else {
            // last step: h only
            float* h_t = h + (size_t)(1 + t * E_ + e0) * H_;
            u64* hd = (u64*)(h_t + (size_t)wr * H_ + wc);
#pragma unroll
            for (int q = 0; q < 4; ++q)
                co_store64(hd + q, *(const u64*)&hF[wr][wc + 2 * q]);
        }

        gbar(bar, (unsigned)(t + 1) * NBLK);
    }

    // ---- root tail: blocks 0..255, root_vecs[b] = relu(eWo[wid] + sum_nei @ Wo_bot) ----
    if (blockIdx.x < B_) {
        const int b = blockIdx.x, d = tid;
        float* sn = (float*)&hF[0][0];      // reuse LDS
        int* ridx = &idx[0][0];
        if (d < NB_) ridx[d] = root_nei[b * NB_ + d];
        __syncthreads();
        if (d < H_) {
            float s = 0.0f;
#pragma unroll
            for (int j = 0; j < NB_; ++j) s += co_loadf(&h[(size_t)ridx[j] * H_ + d]);
            sn[d] = s;
        }
        __syncthreads();
        if (d < H_) {
            float acc = eWo[(size_t)root_wid[b] * H_ + d];
            for (int k = 0; k < H_; ++k)
                acc = fmaf(sn[k], Wo[(size_t)(H_ + k) * H_ + d], acc);
            root_out[(size_t)b * H_ + d] = fmaxf(acc, 0.0f);
        }
    }
}

extern "C" void kernel_launch(void* const* d_in, const int* in_sizes, int n_in,
                              void* d_out, int out_size, void* d_ws, size_t ws_size,
                              hipStream_t stream)
{
    const int*   x_ids    = (const int*)d_in[0];
    const int*   nei_idx  = (const int*)d_in[1];
    const int*   root_wid = (const int*)d_in[2];
    const int*   root_nei = (const int*)d_in[3];
    const float* emb      = (const float*)d_in[4];
    const float* Wz       = (const float*)d_in[5];
    const float* bz       = (const float*)d_in[6];
    const float* Wr       = (const float*)d_in[7];
    const float* Ur       = (const float*)d_in[8];
    const float* bur      = (const float*)d_in[9];
    const float* Wh       = (const float*)d_in[10];
    const float* bh       = (const float*)d_in[11];
    const float* Wo       = (const float*)d_in[12];
    const float* bo       = (const float*)d_in[13];

    float* h        = (float*)d_out;                      // [(1+M), H]
    float* root_out = h + (size_t)(1 + M_) * H_;          // [B, H]

    unsigned* hu = (unsigned*)d_ws;                       // [(1+M), H] packed {h,u} bf16
    float* eWr  = (float*)(hu + (size_t)(1 + M_) * H_);   // [V, H] emb@Wr + bur
    float* eWz  = eWr  + (size_t)V_ * H_;                 // [V, H] emb@Wz_top + bz
    float* eWh  = eWz  + (size_t)V_ * H_;                 // [V, H] emb@Wh_top + bh
    float* eWo  = eWh  + (size_t)V_ * H_;                 // [V, H] emb@Wo_top + bo
    short* Wzt  = (short*)(eWo + (size_t)V_ * H_);        // [256,256] bf16 transposed
    short* Wht  = Wzt + 65536;
    short* Urt  = Wht + 65536;
    unsigned* eWzh = (unsigned*)(Urt + 65536);            // [V, H] packed {bf16(eWz), bf16(eWh)}
    unsigned* bar  = eWzh + (size_t)V_ * H_;              // [1] grid-barrier counter

    k_wconv<<<dim3(769), dim3(256), 0, stream>>>(Wz, Wh, Ur, Wzt, Wht, Urt, h, hu, bar);
    gemm_pre<<<dim3((V_ + 63) / 64, 4, 4), dim3(256), 0, stream>>>(
        emb, Wr, Wz, Wh, Wo, bur, bz, bh, bo, eWr, eWz, eWh, eWo);
    k_pack<<<dim3(V_ * H_ / 256), dim3(256), 0, stream>>>(eWz, eWh, eWzh);

    k_steps_all<<<dim3(NBLK), dim3(512), 0, stream>>>(
        x_ids, nei_idx, h, hu, eWr, eWzh, Wzt, Wht, Urt,
        root_wid, root_nei, eWo, Wo, root_out, bar);
}

// Round 8
// 451.775 us; speedup vs baseline: 2.9774x; 2.9774x over previous
//
#include <hip/hip_runtime.h>
#include <hip/hip_bf16.h>
#include <math.h>

#define T_ 12
#define E_ 8192
#define H_ 256
#define V_ 800
#define B_ 256
#define NB_ 8
#define M_ (T_*E_)
#define TM 32            // message rows per k_step block (weights amortized over 2x rows)
#define HP (H_ + 8)      // bf16 LDS row pad

typedef __attribute__((ext_vector_type(8))) short bf16x8;
typedef __attribute__((ext_vector_type(4))) float f32x4;

#define LOG2E_ 1.44269504088896f

// fast native transcendentals (v_exp_f32 = 2^x, v_rcp_f32)
__device__ __forceinline__ float fexp2_(float x) { return __builtin_amdgcn_exp2f(x); }
__device__ __forceinline__ float frcp_(float x)  { return __builtin_amdgcn_rcpf(x); }
__device__ __forceinline__ float fsig(float x) {
    return frcp_(1.0f + fexp2_(-LOG2E_ * x));
}
__device__ __forceinline__ float ftanh(float x) {
    // tanh(x) = 1 - 2/(exp(2x)+1); large |x| saturates correctly via inf/0
    return 1.0f - 2.0f * frcp_(fexp2_(2.0f * LOG2E_ * x) + 1.0f);
}

// RNE f32 -> bf16 bits
__device__ __forceinline__ short f2bf(float x) {
    unsigned u = __float_as_uint(x);
    unsigned r = (u + 0x7fffu + ((u >> 16) & 1u)) >> 16;
    return (short)r;
}
__device__ __forceinline__ float bf2f(unsigned short s) {
    return __uint_as_float(((unsigned)s) << 16);
}
// packed word: lo16 -> float via <<16, hi16 -> float via mask
__device__ __forceinline__ float hu_h(unsigned v) { return __uint_as_float(v << 16); }
__device__ __forceinline__ float hu_u(unsigned v) { return __uint_as_float(v & 0xffff0000u); }
__device__ __forceinline__ unsigned pack2(float a, float b) {
    return (unsigned)(unsigned short)f2bf(a) | ((unsigned)(unsigned short)f2bf(b) << 16);
}

// Weight prep (+ slot-0 init folded into block 768).
// Wzt[n][k] = Wz[256+k][n], Wht[n][k] = Wh[256+k][n], Urt[n][k] = Ur[k][n], bf16.
__global__ __launch_bounds__(256) void k_wconv(
    const float* __restrict__ Wz, const float* __restrict__ Wh, const float* __restrict__ Ur,
    short* __restrict__ Wzt, short* __restrict__ Wht, short* __restrict__ Urt,
    float* __restrict__ h, unsigned* __restrict__ hu)
{
    if (blockIdx.x == 768) {            // zero padding row (slot 0) of h and hu
        h[threadIdx.x] = 0.0f;
        hu[threadIdx.x] = 0u;
        return;
    }
    int tid = blockIdx.x * 256 + threadIdx.x;
    int w = tid >> 16;
    int idx = tid & 65535;
    int n = idx >> 8, k = idx & 255;
    if (w == 0)      Wzt[idx] = f2bf(Wz[(size_t)(256 + k) * H_ + n]);
    else if (w == 1) Wht[idx] = f2bf(Wh[(size_t)(256 + k) * H_ + n]);
    else             Urt[idx] = f2bf(Ur[(size_t)k * H_ + n]);
}

// Batched prelude: blockIdx.z selects table.
// z=0: eWr (f32) = emb@Wr_bot + bur ; z=3: eWo (f32) = emb@Wo_top + bo
// z=1: lo16 of eWzh = bf16(emb@Wz_top + bz) ; z=2: hi16 of eWzh = bf16(emb@Wh_top + bh)
__global__ __launch_bounds__(256) void gemm_pre(
    const float* __restrict__ emb,
    const float* __restrict__ Wr, const float* __restrict__ Wz,
    const float* __restrict__ Wh, const float* __restrict__ Wo,
    const float* __restrict__ bur, const float* __restrict__ bz,
    const float* __restrict__ bh, const float* __restrict__ bo,
    float* __restrict__ eWr, unsigned* __restrict__ eWzh,
    float* __restrict__ eWo)
{
    const float* Bm; const float* bias;
    switch (blockIdx.z) {
        case 0: Bm = Wr; bias = bur; break;
        case 1: Bm = Wz; bias = bz;  break;
        case 2: Bm = Wh; bias = bh;  break;
        default: Bm = Wo; bias = bo; break;
    }
    __shared__ float As[16][64];
    __shared__ float Bs[16][64];
    const int tid = threadIdx.x;
    const int bm = blockIdx.x * 64;
    const int bn = blockIdx.y * 64;
    const int a_m = tid & 63;
    const int a_k = (tid >> 6) << 2;
    const int b_k = tid >> 4;
    const int b_n = (tid & 15) << 2;
    const int tx = tid & 15, ty = tid >> 4;

    float acc[4][4] = {};
    const bool a_ok = (bm + a_m) < V_;
    const float* Ap = emb + (size_t)(bm + a_m) * H_ + a_k;
    const float* Bp = Bm + (size_t)b_k * H_ + bn + b_n;

    for (int k0 = 0; k0 < H_; k0 += 16) {
        float4 av = a_ok ? *(const float4*)(Ap + k0) : make_float4(0.f, 0.f, 0.f, 0.f);
        float4 bv = *(const float4*)(Bp + (size_t)k0 * H_);
        __syncthreads();
        As[a_k + 0][a_m] = av.x;
        As[a_k + 1][a_m] = av.y;
        As[a_k + 2][a_m] = av.z;
        As[a_k + 3][a_m] = av.w;
        *(float4*)&Bs[b_k][b_n] = bv;
        __syncthreads();
#pragma unroll
        for (int k = 0; k < 16; ++k) {
            const float4 a4 = *(const float4*)&As[k][ty << 2];
            const float4 b4 = *(const float4*)&Bs[k][tx << 2];
            const float ar[4] = {a4.x, a4.y, a4.z, a4.w};
            const float br[4] = {b4.x, b4.y, b4.z, b4.w};
#pragma unroll
            for (int i = 0; i < 4; ++i)
#pragma unroll
                for (int j = 0; j < 4; ++j)
                    acc[i][j] = fmaf(ar[i], br[j], acc[i][j]);
        }
    }

    const int col = bn + (tx << 2);
    const int z = blockIdx.z;
#pragma unroll
    for (int i = 0; i < 4; ++i) {
        const int row = bm + (ty << 2) + i;
        if (row >= V_) break;
        const float v0 = acc[i][0] + bias[col];
        const float v1 = acc[i][1] + bias[col + 1];
        const float v2 = acc[i][2] + bias[col + 2];
        const float v3 = acc[i][3] + bias[col + 3];
        if (z == 0) {
            *(float4*)(eWr + (size_t)row * H_ + col) = make_float4(v0, v1, v2, v3);
        } else if (z == 3) {
            *(float4*)(eWo + (size_t)row * H_ + col) = make_float4(v0, v1, v2, v3);
        } else {
            // pack bf16 halves directly into eWzh (lo16 for z=1/Wz, hi16 for z=2/Wh)
            short* base = (short*)(eWzh + (size_t)row * H_ + col) + (z - 1);
            base[0] = f2bf(v0); base[2] = f2bf(v1);
            base[4] = f2bf(v2); base[6] = f2bf(v3);
        }
    }
}

// Fused step, 512 threads (8 waves), TM=32 rows, ~52 KB LDS, grid 256 blocks.
// Each wave owns a 32-col strip and processes TWO 16-row groups with the SAME
// B-fragments, halving per-row weight traffic vs TM=16 (the launch-mode cost the
// persistent experiments isolated: 384KB/block/step of Wzt/Wht/Urt refetch).
__global__ __launch_bounds__(512, 2) void k_step(
    int t,
    const int* __restrict__ x_ids, const int* __restrict__ nei_idx,
    float* __restrict__ h, unsigned* __restrict__ hu,
    const float* __restrict__ eWr, const unsigned* __restrict__ eWzh,
    const short* __restrict__ Wzt, const short* __restrict__ Wht,
    const short* __restrict__ Urt,
    int do_ur)
{
    __shared__ int   idx[TM][NB_];
    __shared__ int   xw[TM];
    __shared__ short shB[TM][HP];   // sumh bf16 (A-frag + epilogue linear term)
    __shared__ short sgB[TM][HP];   // sumg bf16 (A-frag)
    __shared__ short hB[TM][HP];    // h_t bf16 (A-frag Ur + hu pack)

    const int tid = threadIdx.x;
    const int e0 = blockIdx.x * TM;

    if (tid < TM * NB_) {
        int r = tid >> 3, j = tid & 7;
        idx[r][j] = nei_idx[((size_t)t * E_ + e0 + r) * NB_ + j];
    }
    if (tid < TM) xw[tid] = x_ids[t * E_ + e0 + tid];
    __syncthreads();

    // ---- gather: thread = (4-col group, 4-row group); 2 rows per batch ----
    {
        const int c0 = (tid & 63) * 4;       // 64 col-groups x 4 cols = 256 cols
        const int rbase = (tid >> 6) * 4;    // 8 groups x 4 rows = 32 rows
        if (t == 0) {
#pragma unroll
            for (int rr = 0; rr < 4; ++rr) {
                *(uint2*)&shB[rbase + rr][c0] = make_uint2(0u, 0u);
                *(uint2*)&sgB[rbase + rr][c0] = make_uint2(0u, 0u);
            }
        } else {
            for (int rr = 0; rr < 4; rr += 2) {
                const int ra = rbase + rr, rb = ra + 1;
                uint4 va[NB_], vb[NB_];
#pragma unroll
                for (int j = 0; j < NB_; ++j)
                    va[j] = *(const uint4*)(hu + (size_t)idx[ra][j] * H_ + c0);
#pragma unroll
                for (int j = 0; j < NB_; ++j)
                    vb[j] = *(const uint4*)(hu + (size_t)idx[rb][j] * H_ + c0);
                const float4 r1a = *(const float4*)(eWr + (size_t)xw[ra] * H_ + c0);
                const float4 r1b = *(const float4*)(eWr + (size_t)xw[rb] * H_ + c0);

                float sa0 = 0.f, sa1 = 0.f, sa2 = 0.f, sa3 = 0.f;
                float ga0 = 0.f, ga1 = 0.f, ga2 = 0.f, ga3 = 0.f;
#pragma unroll
                for (int j = 0; j < NB_; ++j) {
                    const float h0 = hu_h(va[j].x); sa0 += h0;
                    ga0 = fmaf(fsig(r1a.x + hu_u(va[j].x)), h0, ga0);
                    const float h1 = hu_h(va[j].y); sa1 += h1;
                    ga1 = fmaf(fsig(r1a.y + hu_u(va[j].y)), h1, ga1);
                    const float h2 = hu_h(va[j].z); sa2 += h2;
                    ga2 = fmaf(fsig(r1a.z + hu_u(va[j].z)), h2, ga2);
                    const float h3 = hu_h(va[j].w); sa3 += h3;
                    ga3 = fmaf(fsig(r1a.w + hu_u(va[j].w)), h3, ga3);
                }
                *(uint2*)&shB[ra][c0] = make_uint2(pack2(sa0, sa1), pack2(sa2, sa3));
                *(uint2*)&sgB[ra][c0] = make_uint2(pack2(ga0, ga1), pack2(ga2, ga3));

                float sb0 = 0.f, sb1 = 0.f, sb2 = 0.f, sb3 = 0.f;
                float gb0 = 0.f, gb1 = 0.f, gb2 = 0.f, gb3 = 0.f;
#pragma unroll
                for (int j = 0; j < NB_; ++j) {
                    const float h0 = hu_h(vb[j].x); sb0 += h0;
                    gb0 = fmaf(fsig(r1b.x + hu_u(vb[j].x)), h0, gb0);
                    const float h1 = hu_h(vb[j].y); sb1 += h1;
                    gb1 = fmaf(fsig(r1b.y + hu_u(vb[j].y)), h1, gb1);
                    const float h2 = hu_h(vb[j].z); sb2 += h2;
                    gb2 = fmaf(fsig(r1b.z + hu_u(vb[j].z)), h2, gb2);
                    const float h3 = hu_h(vb[j].w); sb3 += h3;
                    gb3 = fmaf(fsig(r1b.w + hu_u(vb[j].w)), h3, gb3);
                }
                *(uint2*)&shB[rb][c0] = make_uint2(pack2(sb0, sb1), pack2(sb2, sb3));
                *(uint2*)&sgB[rb][c0] = make_uint2(pack2(gb0, gb1), pack2(gb2, gb3));
            }
        }
    }
    __syncthreads();

    // ---- MFMA: wave owns 32-col strip; 2 row-groups share B-frags ----
    const int lane = tid & 63;
    const int wave = tid >> 6;           // 0..7
    const int n0 = wave * 32;
    const int quad = lane >> 4, c = lane & 15;
    const int kq = quad * 8;

    f32x4 accZ[2][2], accH[2][2];        // [row-group][ni]
#pragma unroll
    for (int rg = 0; rg < 2; ++rg)
#pragma unroll
        for (int i = 0; i < 2; ++i) { accZ[rg][i] = (f32x4)(0.0f); accH[rg][i] = (f32x4)(0.0f); }

#pragma unroll
    for (int k0 = 0; k0 < H_; k0 += 32) {
        const bf16x8 a1lo = *(const bf16x8*)&shB[c][k0 + kq];
        const bf16x8 a2lo = *(const bf16x8*)&sgB[c][k0 + kq];
        const bf16x8 a1hi = *(const bf16x8*)&shB[16 + c][k0 + kq];
        const bf16x8 a2hi = *(const bf16x8*)&sgB[16 + c][k0 + kq];
#pragma unroll
        for (int ni = 0; ni < 2; ++ni) {
            const size_t boff = (size_t)(n0 + ni * 16 + c) * H_ + k0 + kq;
            const bf16x8 b1 = *(const bf16x8*)(Wzt + boff);
            const bf16x8 b2 = *(const bf16x8*)(Wht + boff);
            accZ[0][ni] = __builtin_amdgcn_mfma_f32_16x16x32_bf16(a1lo, b1, accZ[0][ni], 0, 0, 0);
            accH[0][ni] = __builtin_amdgcn_mfma_f32_16x16x32_bf16(a2lo, b2, accH[0][ni], 0, 0, 0);
            accZ[1][ni] = __builtin_amdgcn_mfma_f32_16x16x32_bf16(a1hi, b1, accZ[1][ni], 0, 0, 0);
            accH[1][ni] = __builtin_amdgcn_mfma_f32_16x16x32_bf16(a2hi, b2, accH[1][ni], 0, 0, 0);
        }
    }

    // epilogue: h_t = (1-z)*sumh + z*pre, in-register per C-cell
    float* h_t = h + (size_t)(1 + t * E_) * H_;
#pragma unroll
    for (int rg = 0; rg < 2; ++rg) {
#pragma unroll
        for (int reg = 0; reg < 4; ++reg) {
            const int r = rg * 16 + quad * 4 + reg;
            const int xr = xw[r];
#pragma unroll
            for (int ni = 0; ni < 2; ++ni) {
                const int col = n0 + ni * 16 + c;
                const unsigned zh = eWzh[(size_t)xr * H_ + col];
                const float z   = fsig(accZ[rg][ni][reg] + hu_h(zh));
                const float pre = ftanh(accH[rg][ni][reg] + hu_u(zh));
                const float hv = (1.0f - z) * bf2f((unsigned short)shB[r][col]) + z * pre;
                h_t[(size_t)(e0 + r) * H_ + col] = hv;
                hB[r][col] = f2bf(hv);
            }
        }
    }

    if (!do_ur) return;
    __syncthreads();

    // ---- Ur MFMA: u = h_t @ Ur; store packed {h_bf16, u_bf16} ----
    {
        f32x4 accU[2][2];
#pragma unroll
        for (int rg = 0; rg < 2; ++rg) { accU[rg][0] = (f32x4)(0.0f); accU[rg][1] = (f32x4)(0.0f); }
#pragma unroll
        for (int k0 = 0; k0 < H_; k0 += 32) {
            const bf16x8 alo = *(const bf16x8*)&hB[c][k0 + kq];
            const bf16x8 ahi = *(const bf16x8*)&hB[16 + c][k0 + kq];
#pragma unroll
            for (int ni = 0; ni < 2; ++ni) {
                const bf16x8 b = *(const bf16x8*)(Urt + (size_t)(n0 + ni * 16 + c) * H_ + k0 + kq);
                accU[0][ni] = __builtin_amdgcn_mfma_f32_16x16x32_bf16(alo, b, accU[0][ni], 0, 0, 0);
                accU[1][ni] = __builtin_amdgcn_mfma_f32_16x16x32_bf16(ahi, b, accU[1][ni], 0, 0, 0);
            }
        }
        unsigned* hu_t = hu + (size_t)(1 + t * E_) * H_;
#pragma unroll
        for (int rg = 0; rg < 2; ++rg) {
#pragma unroll
            for (int reg = 0; reg < 4; ++reg) {
                const int r = rg * 16 + quad * 4 + reg;
#pragma unroll
                for (int ni = 0; ni < 2; ++ni) {
                    const int col = n0 + ni * 16 + c;
                    const unsigned ubits = (unsigned)(unsigned short)f2bf(accU[rg][ni][reg]);
                    const unsigned hbits = (unsigned)(unsigned short)hB[r][col];
                    hu_t[(size_t)(e0 + r) * H_ + col] = (ubits << 16) | hbits;
                }
            }
        }
    }
}

// root_vecs[b] = relu(eWo[root_wid[b]] + sum_nei @ Wo_bot)   (eWo includes bo)
__global__ __launch_bounds__(256) void k_root(
    const int* __restrict__ root_wid, const int* __restrict__ root_nei,
    const float* __restrict__ h, const float* __restrict__ eWo,
    const float* __restrict__ Wo, float* __restrict__ out)
{
    const int b = blockIdx.x, d = threadIdx.x;
    __shared__ float sn[H_];
    __shared__ int idx[NB_];
    if (d < NB_) idx[d] = root_nei[b * NB_ + d];
    __syncthreads();
    float s = 0.0f;
#pragma unroll
    for (int j = 0; j < NB_; ++j) s += h[(size_t)idx[j] * H_ + d];
    sn[d] = s;
    __syncthreads();
    float acc = eWo[(size_t)root_wid[b] * H_ + d];
    for (int k = 0; k < H_; ++k)
        acc = fmaf(sn[k], Wo[(size_t)(H_ + k) * H_ + d], acc);
    out[(size_t)b * H_ + d] = fmaxf(acc, 0.0f);
}

extern "C" void kernel_launch(void* const* d_in, const int* in_sizes, int n_in,
                              void* d_out, int out_size, void* d_ws, size_t ws_size,
                              hipStream_t stream)
{
    const int*   x_ids    = (const int*)d_in[0];
    const int*   nei_idx  = (const int*)d_in[1];
    const int*   root_wid = (const int*)d_in[2];
    const int*   root_nei = (const int*)d_in[3];
    const float* emb      = (const float*)d_in[4];
    const float* Wz       = (const float*)d_in[5];
    const float* bz       = (const float*)d_in[6];
    const float* Wr       = (const float*)d_in[7];
    const float* Ur       = (const float*)d_in[8];
    const float* bur      = (const float*)d_in[9];
    const float* Wh       = (const float*)d_in[10];
    const float* bh       = (const float*)d_in[11];
    const float* Wo       = (const float*)d_in[12];
    const float* bo       = (const float*)d_in[13];

    float* h        = (float*)d_out;                      // [(1+M), H]
    float* root_out = h + (size_t)(1 + M_) * H_;          // [B, H]

    unsigned* hu = (unsigned*)d_ws;                       // [(1+M), H] packed {h,u} bf16
    float* eWr  = (float*)(hu + (size_t)(1 + M_) * H_);   // [V, H] emb@Wr + bur
    float* eWo  = eWr  + (size_t)V_ * H_;                 // [V, H] emb@Wo_top + bo
    unsigned* eWzh = (unsigned*)(eWo + (size_t)V_ * H_);  // [V, H] packed {bf16(eWz), bf16(eWh)}
    short* Wzt  = (short*)(eWzh + (size_t)V_ * H_);       // [256,256] bf16 transposed
    short* Wht  = Wzt + 65536;
    short* Urt  = Wht + 65536;

    k_wconv<<<dim3(769), dim3(256), 0, stream>>>(Wz, Wh, Ur, Wzt, Wht, Urt, h, hu);
    gemm_pre<<<dim3((V_ + 63) / 64, 4, 4), dim3(256), 0, stream>>>(
        emb, Wr, Wz, Wh, Wo, bur, bz, bh, bo, eWr, eWzh, eWo);

    for (int t = 0; t < T_; ++t) {
        k_step<<<dim3(E_ / TM), dim3(512), 0, stream>>>(
            t, x_ids, nei_idx, h, hu, eWr, eWzh, Wzt, Wht, Urt,
            (t < T_ - 1) ? 1 : 0);
    }

    k_root<<<dim3(B_), dim3(256), 0, stream>>>(root_wid, root_nei, h, eWo, Wo, root_out);
}

// Round 9
// 445.248 us; speedup vs baseline: 3.0210x; 1.0147x over previous
//
#include <hip/hip_runtime.h>
#include <hip/hip_bf16.h>
#include <math.h>

#define T_ 12
#define E_ 8192
#define H_ 256
#define V_ 800
#define B_ 256
#define NB_ 8
#define M_ (T_*E_)
#define TM 32            // message rows per k_step block (weights amortized over 2x rows)
#define HP (H_ + 8)      // bf16 LDS row pad

typedef __attribute__((ext_vector_type(8))) short bf16x8;
typedef __attribute__((ext_vector_type(4))) float f32x4;

#define LOG2E_ 1.44269504088896f

// fast native transcendentals (v_exp_f32 = 2^x, v_rcp_f32)
__device__ __forceinline__ float fexp2_(float x) { return __builtin_amdgcn_exp2f(x); }
__device__ __forceinline__ float frcp_(float x)  { return __builtin_amdgcn_rcpf(x); }
__device__ __forceinline__ float fsig(float x) {
    return frcp_(1.0f + fexp2_(-LOG2E_ * x));
}
__device__ __forceinline__ float ftanh(float x) {
    // tanh(x) = 1 - 2/(exp(2x)+1); large |x| saturates correctly via inf/0
    return 1.0f - 2.0f * frcp_(fexp2_(2.0f * LOG2E_ * x) + 1.0f);
}

// RNE f32 -> bf16 bits
__device__ __forceinline__ short f2bf(float x) {
    unsigned u = __float_as_uint(x);
    unsigned r = (u + 0x7fffu + ((u >> 16) & 1u)) >> 16;
    return (short)r;
}
__device__ __forceinline__ float bf2f(unsigned short s) {
    return __uint_as_float(((unsigned)s) << 16);
}
// packed word: lo16 -> float via <<16, hi16 -> float via mask
__device__ __forceinline__ float hu_h(unsigned v) { return __uint_as_float(v << 16); }
__device__ __forceinline__ float hu_u(unsigned v) { return __uint_as_float(v & 0xffff0000u); }
__device__ __forceinline__ unsigned pack2(float a, float b) {
    return (unsigned)(unsigned short)f2bf(a) | ((unsigned)(unsigned short)f2bf(b) << 16);
}

// Weight prep (+ slot-0 init folded into block 768).
// Wzt[n][k] = Wz[256+k][n], Wht[n][k] = Wh[256+k][n], Urt[n][k] = Ur[k][n], bf16.
__global__ __launch_bounds__(256) void k_wconv(
    const float* __restrict__ Wz, const float* __restrict__ Wh, const float* __restrict__ Ur,
    short* __restrict__ Wzt, short* __restrict__ Wht, short* __restrict__ Urt,
    float* __restrict__ h, unsigned* __restrict__ hu)
{
    if (blockIdx.x == 768) {            // zero padding row (slot 0) of h and hu
        h[threadIdx.x] = 0.0f;
        hu[threadIdx.x] = 0u;
        return;
    }
    int tid = blockIdx.x * 256 + threadIdx.x;
    int w = tid >> 16;
    int idx = tid & 65535;
    int n = idx >> 8, k = idx & 255;
    if (w == 0)      Wzt[idx] = f2bf(Wz[(size_t)(256 + k) * H_ + n]);
    else if (w == 1) Wht[idx] = f2bf(Wh[(size_t)(256 + k) * H_ + n]);
    else             Urt[idx] = f2bf(Ur[(size_t)k * H_ + n]);
}

// Batched prelude: blockIdx.z selects table.
// z=0: eWr (f32) = emb@Wr_bot + bur ; z=3: eWo (f32) = emb@Wo_top + bo
// z=1: lo16 of eWzh = bf16(emb@Wz_top + bz) ; z=2: hi16 of eWzh = bf16(emb@Wh_top + bh)
__global__ __launch_bounds__(256) void gemm_pre(
    const float* __restrict__ emb,
    const float* __restrict__ Wr, const float* __restrict__ Wz,
    const float* __restrict__ Wh, const float* __restrict__ Wo,
    const float* __restrict__ bur, const float* __restrict__ bz,
    const float* __restrict__ bh, const float* __restrict__ bo,
    float* __restrict__ eWr, unsigned* __restrict__ eWzh,
    float* __restrict__ eWo)
{
    const float* Bm; const float* bias;
    switch (blockIdx.z) {
        case 0: Bm = Wr; bias = bur; break;
        case 1: Bm = Wz; bias = bz;  break;
        case 2: Bm = Wh; bias = bh;  break;
        default: Bm = Wo; bias = bo; break;
    }
    __shared__ float As[16][64];
    __shared__ float Bs[16][64];
    const int tid = threadIdx.x;
    const int bm = blockIdx.x * 64;
    const int bn = blockIdx.y * 64;
    const int a_m = tid & 63;
    const int a_k = (tid >> 6) << 2;
    const int b_k = tid >> 4;
    const int b_n = (tid & 15) << 2;
    const int tx = tid & 15, ty = tid >> 4;

    float acc[4][4] = {};
    const bool a_ok = (bm + a_m) < V_;
    const float* Ap = emb + (size_t)(bm + a_m) * H_ + a_k;
    const float* Bp = Bm + (size_t)b_k * H_ + bn + b_n;

    for (int k0 = 0; k0 < H_; k0 += 16) {
        float4 av = a_ok ? *(const float4*)(Ap + k0) : make_float4(0.f, 0.f, 0.f, 0.f);
        float4 bv = *(const float4*)(Bp + (size_t)k0 * H_);
        __syncthreads();
        As[a_k + 0][a_m] = av.x;
        As[a_k + 1][a_m] = av.y;
        As[a_k + 2][a_m] = av.z;
        As[a_k + 3][a_m] = av.w;
        *(float4*)&Bs[b_k][b_n] = bv;
        __syncthreads();
#pragma unroll
        for (int k = 0; k < 16; ++k) {
            const float4 a4 = *(const float4*)&As[k][ty << 2];
            const float4 b4 = *(const float4*)&Bs[k][tx << 2];
            const float ar[4] = {a4.x, a4.y, a4.z, a4.w};
            const float br[4] = {b4.x, b4.y, b4.z, b4.w};
#pragma unroll
            for (int i = 0; i < 4; ++i)
#pragma unroll
                for (int j = 0; j < 4; ++j)
                    acc[i][j] = fmaf(ar[i], br[j], acc[i][j]);
        }
    }

    const int col = bn + (tx << 2);
    const int z = blockIdx.z;
#pragma unroll
    for (int i = 0; i < 4; ++i) {
        const int row = bm + (ty << 2) + i;
        if (row >= V_) break;
        const float v0 = acc[i][0] + bias[col];
        const float v1 = acc[i][1] + bias[col + 1];
        const float v2 = acc[i][2] + bias[col + 2];
        const float v3 = acc[i][3] + bias[col + 3];
        if (z == 0) {
            *(float4*)(eWr + (size_t)row * H_ + col) = make_float4(v0, v1, v2, v3);
        } else if (z == 3) {
            *(float4*)(eWo + (size_t)row * H_ + col) = make_float4(v0, v1, v2, v3);
        } else {
            // pack bf16 halves directly into eWzh (lo16 for z=1/Wz, hi16 for z=2/Wh)
            short* base = (short*)(eWzh + (size_t)row * H_ + col) + (z - 1);
            base[0] = f2bf(v0); base[2] = f2bf(v1);
            base[4] = f2bf(v2); base[6] = f2bf(v3);
        }
    }
}

// Fused step, 512 threads (8 waves), TM=32 rows, ~52 KB LDS, grid 256 blocks.
// Each wave owns a 32-col strip and processes TWO 16-row groups with the SAME
// B-fragments, halving per-row weight traffic vs TM=16. h stores are NON-TEMPORAL:
// h is write-once (re-read only by k_root, 2MB of 96MB), and keeping it out of
// L2/L3 preserves the hu gather pool + weights/tables as L3 residents across steps.
__global__ __launch_bounds__(512, 2) void k_step(
    int t,
    const int* __restrict__ x_ids, const int* __restrict__ nei_idx,
    float* __restrict__ h, unsigned* __restrict__ hu,
    const float* __restrict__ eWr, const unsigned* __restrict__ eWzh,
    const short* __restrict__ Wzt, const short* __restrict__ Wht,
    const short* __restrict__ Urt,
    int do_ur)
{
    __shared__ int   idx[TM][NB_];
    __shared__ int   xw[TM];
    __shared__ short shB[TM][HP];   // sumh bf16 (A-frag + epilogue linear term)
    __shared__ short sgB[TM][HP];   // sumg bf16 (A-frag)
    __shared__ short hB[TM][HP];    // h_t bf16 (A-frag Ur + hu pack)

    const int tid = threadIdx.x;
    const int e0 = blockIdx.x * TM;

    if (tid < TM * NB_) {
        int r = tid >> 3, j = tid & 7;
        idx[r][j] = nei_idx[((size_t)t * E_ + e0 + r) * NB_ + j];
    }
    if (tid < TM) xw[tid] = x_ids[t * E_ + e0 + tid];
    __syncthreads();

    // ---- gather: thread = (4-col group, 4-row group); 2 rows per batch ----
    {
        const int c0 = (tid & 63) * 4;       // 64 col-groups x 4 cols = 256 cols
        const int rbase = (tid >> 6) * 4;    // 8 groups x 4 rows = 32 rows
        if (t == 0) {
#pragma unroll
            for (int rr = 0; rr < 4; ++rr) {
                *(uint2*)&shB[rbase + rr][c0] = make_uint2(0u, 0u);
                *(uint2*)&sgB[rbase + rr][c0] = make_uint2(0u, 0u);
            }
        } else {
            for (int rr = 0; rr < 4; rr += 2) {
                const int ra = rbase + rr, rb = ra + 1;
                uint4 va[NB_], vb[NB_];
#pragma unroll
                for (int j = 0; j < NB_; ++j)
                    va[j] = *(const uint4*)(hu + (size_t)idx[ra][j] * H_ + c0);
#pragma unroll
                for (int j = 0; j < NB_; ++j)
                    vb[j] = *(const uint4*)(hu + (size_t)idx[rb][j] * H_ + c0);
                const float4 r1a = *(const float4*)(eWr + (size_t)xw[ra] * H_ + c0);
                const float4 r1b = *(const float4*)(eWr + (size_t)xw[rb] * H_ + c0);

                float sa0 = 0.f, sa1 = 0.f, sa2 = 0.f, sa3 = 0.f;
                float ga0 = 0.f, ga1 = 0.f, ga2 = 0.f, ga3 = 0.f;
#pragma unroll
                for (int j = 0; j < NB_; ++j) {
                    const float h0 = hu_h(va[j].x); sa0 += h0;
                    ga0 = fmaf(fsig(r1a.x + hu_u(va[j].x)), h0, ga0);
                    const float h1 = hu_h(va[j].y); sa1 += h1;
                    ga1 = fmaf(fsig(r1a.y + hu_u(va[j].y)), h1, ga1);
                    const float h2 = hu_h(va[j].z); sa2 += h2;
                    ga2 = fmaf(fsig(r1a.z + hu_u(va[j].z)), h2, ga2);
                    const float h3 = hu_h(va[j].w); sa3 += h3;
                    ga3 = fmaf(fsig(r1a.w + hu_u(va[j].w)), h3, ga3);
                }
                *(uint2*)&shB[ra][c0] = make_uint2(pack2(sa0, sa1), pack2(sa2, sa3));
                *(uint2*)&sgB[ra][c0] = make_uint2(pack2(ga0, ga1), pack2(ga2, ga3));

                float sb0 = 0.f, sb1 = 0.f, sb2 = 0.f, sb3 = 0.f;
                float gb0 = 0.f, gb1 = 0.f, gb2 = 0.f, gb3 = 0.f;
#pragma unroll
                for (int j = 0; j < NB_; ++j) {
                    const float h0 = hu_h(vb[j].x); sb0 += h0;
                    gb0 = fmaf(fsig(r1b.x + hu_u(vb[j].x)), h0, gb0);
                    const float h1 = hu_h(vb[j].y); sb1 += h1;
                    gb1 = fmaf(fsig(r1b.y + hu_u(vb[j].y)), h1, gb1);
                    const float h2 = hu_h(vb[j].z); sb2 += h2;
                    gb2 = fmaf(fsig(r1b.z + hu_u(vb[j].z)), h2, gb2);
                    const float h3 = hu_h(vb[j].w); sb3 += h3;
                    gb3 = fmaf(fsig(r1b.w + hu_u(vb[j].w)), h3, gb3);
                }
                *(uint2*)&shB[rb][c0] = make_uint2(pack2(sb0, sb1), pack2(sb2, sb3));
                *(uint2*)&sgB[rb][c0] = make_uint2(pack2(gb0, gb1), pack2(gb2, gb3));
            }
        }
    }
    __syncthreads();

    // ---- MFMA: wave owns 32-col strip; 2 row-groups share B-frags ----
    const int lane = tid & 63;
    const int wave = tid >> 6;           // 0..7
    const int n0 = wave * 32;
    const int quad = lane >> 4, c = lane & 15;
    const int kq = quad * 8;

    f32x4 accZ[2][2], accH[2][2];        // [row-group][ni]
#pragma unroll
    for (int rg = 0; rg < 2; ++rg)
#pragma unroll
        for (int i = 0; i < 2; ++i) { accZ[rg][i] = (f32x4)(0.0f); accH[rg][i] = (f32x4)(0.0f); }

#pragma unroll
    for (int k0 = 0; k0 < H_; k0 += 32) {
        const bf16x8 a1lo = *(const bf16x8*)&shB[c][k0 + kq];
        const bf16x8 a2lo = *(const bf16x8*)&sgB[c][k0 + kq];
        const bf16x8 a1hi = *(const bf16x8*)&shB[16 + c][k0 + kq];
        const bf16x8 a2hi = *(const bf16x8*)&sgB[16 + c][k0 + kq];
#pragma unroll
        for (int ni = 0; ni < 2; ++ni) {
            const size_t boff = (size_t)(n0 + ni * 16 + c) * H_ + k0 + kq;
            const bf16x8 b1 = *(const bf16x8*)(Wzt + boff);
            const bf16x8 b2 = *(const bf16x8*)(Wht + boff);
            accZ[0][ni] = __builtin_amdgcn_mfma_f32_16x16x32_bf16(a1lo, b1, accZ[0][ni], 0, 0, 0);
            accH[0][ni] = __builtin_amdgcn_mfma_f32_16x16x32_bf16(a2lo, b2, accH[0][ni], 0, 0, 0);
            accZ[1][ni] = __builtin_amdgcn_mfma_f32_16x16x32_bf16(a1hi, b1, accZ[1][ni], 0, 0, 0);
            accH[1][ni] = __builtin_amdgcn_mfma_f32_16x16x32_bf16(a2hi, b2, accH[1][ni], 0, 0, 0);
        }
    }

    // epilogue: h_t = (1-z)*sumh + z*pre, in-register per C-cell
    float* h_t = h + (size_t)(1 + t * E_) * H_;
#pragma unroll
    for (int rg = 0; rg < 2; ++rg) {
#pragma unroll
        for (int reg = 0; reg < 4; ++reg) {
            const int r = rg * 16 + quad * 4 + reg;
            const int xr = xw[r];
#pragma unroll
            for (int ni = 0; ni < 2; ++ni) {
                const int col = n0 + ni * 16 + c;
                const unsigned zh = eWzh[(size_t)xr * H_ + col];
                const float z   = fsig(accZ[rg][ni][reg] + hu_h(zh));
                const float pre = ftanh(accH[rg][ni][reg] + hu_u(zh));
                const float hv = (1.0f - z) * bf2f((unsigned short)shB[r][col]) + z * pre;
                __builtin_nontemporal_store(hv, &h_t[(size_t)(e0 + r) * H_ + col]);
                hB[r][col] = f2bf(hv);
            }
        }
    }

    if (!do_ur) return;
    __syncthreads();

    // ---- Ur MFMA: u = h_t @ Ur; store packed {h_bf16, u_bf16} ----
    {
        f32x4 accU[2][2];
#pragma unroll
        for (int rg = 0; rg < 2; ++rg) { accU[rg][0] = (f32x4)(0.0f); accU[rg][1] = (f32x4)(0.0f); }
#pragma unroll
        for (int k0 = 0; k0 < H_; k0 += 32) {
            const bf16x8 alo = *(const bf16x8*)&hB[c][k0 + kq];
            const bf16x8 ahi = *(const bf16x8*)&hB[16 + c][k0 + kq];
#pragma unroll
            for (int ni = 0; ni < 2; ++ni) {
                const bf16x8 b = *(const bf16x8*)(Urt + (size_t)(n0 + ni * 16 + c) * H_ + k0 + kq);
                accU[0][ni] = __builtin_amdgcn_mfma_f32_16x16x32_bf16(alo, b, accU[0][ni], 0, 0, 0);
                accU[1][ni] = __builtin_amdgcn_mfma_f32_16x16x32_bf16(ahi, b, accU[1][ni], 0, 0, 0);
            }
        }
        unsigned* hu_t = hu + (size_t)(1 + t * E_) * H_;
#pragma unroll
        for (int rg = 0; rg < 2; ++rg) {
#pragma unroll
            for (int reg = 0; reg < 4; ++reg) {
                const int r = rg * 16 + quad * 4 + reg;
#pragma unroll
                for (int ni = 0; ni < 2; ++ni) {
                    const int col = n0 + ni * 16 + c;
                    const unsigned ubits = (unsigned)(unsigned short)f2bf(accU[rg][ni][reg]);
                    const unsigned hbits = (unsigned)(unsigned short)hB[r][col];
                    hu_t[(size_t)(e0 + r) * H_ + col] = (ubits << 16) | hbits;
                }
            }
        }
    }
}

// root_vecs[b] = relu(eWo[root_wid[b]] + sum_nei @ Wo_bot)   (eWo includes bo)
__global__ __launch_bounds__(256) void k_root(
    const int* __restrict__ root_wid, const int* __restrict__ root_nei,
    const float* __restrict__ h, const float* __restrict__ eWo,
    const float* __restrict__ Wo, float* __restrict__ out)
{
    const int b = blockIdx.x, d = threadIdx.x;
    __shared__ float sn[H_];
    __shared__ int idx[NB_];
    if (d < NB_) idx[d] = root_nei[b * NB_ + d];
    __syncthreads();
    float s = 0.0f;
#pragma unroll
    for (int j = 0; j < NB_; ++j) s += h[(size_t)idx[j] * H_ + d];
    sn[d] = s;
    __syncthreads();
    float acc = eWo[(size_t)root_wid[b] * H_ + d];
    for (int k = 0; k < H_; ++k)
        acc = fmaf(sn[k], Wo[(size_t)(H_ + k) * H_ + d], acc);
    out[(size_t)b * H_ + d] = fmaxf(acc, 0.0f);
}

extern "C" void kernel_launch(void* const* d_in, const int* in_sizes, int n_in,
                              void* d_out, int out_size, void* d_ws, size_t ws_size,
                              hipStream_t stream)
{
    const int*   x_ids    = (const int*)d_in[0];
    const int*   nei_idx  = (const int*)d_in[1];
    const int*   root_wid = (const int*)d_in[2];
    const int*   root_nei = (const int*)d_in[3];
    const float* emb      = (const float*)d_in[4];
    const float* Wz       = (const float*)d_in[5];
    const float* bz       = (const float*)d_in[6];
    const float* Wr       = (const float*)d_in[7];
    const float* Ur       = (const float*)d_in[8];
    const float* bur      = (const float*)d_in[9];
    const float* Wh       = (const float*)d_in[10];
    const float* bh       = (const float*)d_in[11];
    const float* Wo       = (const float*)d_in[12];
    const float* bo       = (const float*)d_in[13];

    float* h        = (float*)d_out;                      // [(1+M), H]
    float* root_out = h + (size_t)(1 + M_) * H_;          // [B, H]

    unsigned* hu = (unsigned*)d_ws;                       // [(1+M), H] packed {h,u} bf16
    float* eWr  = (float*)(hu + (size_t)(1 + M_) * H_);   // [V, H] emb@Wr + bur
    float* eWo  = eWr  + (size_t)V_ * H_;                 // [V, H] emb@Wo_top + bo
    unsigned* eWzh = (unsigned*)(eWo + (size_t)V_ * H_);  // [V, H] packed {bf16(eWz), bf16(eWh)}
    short* Wzt  = (short*)(eWzh + (size_t)V_ * H_);       // [256,256] bf16 transposed
    short* Wht  = Wzt + 65536;
    short* Urt  = Wht + 65536;

    k_wconv<<<dim3(769), dim3(256), 0, stream>>>(Wz, Wh, Ur, Wzt, Wht, Urt, h, hu);
    gemm_pre<<<dim3((V_ + 63) / 64, 4, 4), dim3(256), 0, stream>>>(
        emb, Wr, Wz, Wh, Wo, bur, bz, bh, bo, eWr, eWzh, eWo);

    for (int t = 0; t < T_; ++t) {
        k_step<<<dim3(E_ / TM), dim3(512), 0, stream>>>(
            t, x_ids, nei_idx, h, hu, eWr, eWzh, Wzt, Wht, Urt,
            (t < T_ - 1) ? 1 : 0);
    }

    k_root<<<dim3(B_), dim3(256), 0, stream>>>(root_wid, root_nei, h, eWo, Wo, root_out);
}